// Round 3
// baseline (180.711 us; speedup 1.0000x reference)
//
#include <hip/hip_runtime.h>
#include <hip/hip_bf16.h>

#define CELLS 27
#define CIN   32
#define FOUT  64
#define M_OUT 150000
#define N_INP 150000
#define ZROW  N_INP                       /* zero feature row */
#define PPW   32                          /* points per wave */
#define NWAVE ((M_OUT + PPW - 1) / PPW)   /* 4688 */
#define NBLK  ((NWAVE + 3) / 4)           /* 1172 */
#define WT_ELEMS (CELLS * CIN * FOUT)     /* 55296 */
#define WT_BYTES (WT_ELEMS * 2)
#define FB_ROWS  (N_INP + 1)
#define FB_BYTES (FB_ROWS * CIN * 2)

typedef __attribute__((ext_vector_type(4))) float f32x4;
typedef __attribute__((ext_vector_type(8))) short bf16x8;

__device__ __forceinline__ short f2bf(float x) {
    union { __hip_bfloat16 h; short s; } u;
    u.h = __float2bfloat16(x);
    return u.s;
}

// Fused prep: fb[i][c] = bf16(feat[i][c]*imp[i]) (+ zero row), and
// Wt[cell][fout][cin] = bf16(W[cell][cin][fout]).
__global__ __launch_bounds__(256) void prep_kernel(const float* __restrict__ W,
                                                   const float* __restrict__ feat,
                                                   const float* __restrict__ imp,
                                                   unsigned short* __restrict__ Wt,
                                                   unsigned short* __restrict__ fb) {
    int t = blockIdx.x * 256 + threadIdx.x;
    if (t < FB_ROWS * 4) {
        int i = t >> 2, c = t & 3;
        bf16x8 o = {0, 0, 0, 0, 0, 0, 0, 0};
        if (i < N_INP) {
            float w = imp[i];
            const float* fp = feat + (size_t)i * CIN + c * 8;
            f32x4 f0 = *(const f32x4*)fp;
            f32x4 f1 = *(const f32x4*)(fp + 4);
            o[0] = f2bf(f0.x * w); o[1] = f2bf(f0.y * w);
            o[2] = f2bf(f0.z * w); o[3] = f2bf(f0.w * w);
            o[4] = f2bf(f1.x * w); o[5] = f2bf(f1.y * w);
            o[6] = f2bf(f1.z * w); o[7] = f2bf(f1.w * w);
        }
        *(bf16x8*)(fb + (size_t)i * CIN + c * 8) = o;
    } else {
        int u = t - FB_ROWS * 4;
        if (u < WT_ELEMS) {
            int cell = u >> 11;
            int rem  = u & 2047;
            int cin  = rem >> 6;
            int fout = rem & 63;
            Wt[cell * 2048 + fout * 32 + cin] = (unsigned short)f2bf(W[u]);
        }
    }
}

#define CELL_OF(k) (((k) % 3) * 9 + (((k) / 3) % 3) * 3 + ((k) / 9))

__global__ __launch_bounds__(256) void conv32_kernel(
        const float* __restrict__ opos,
        const float* __restrict__ ipos,
        const int*   __restrict__ nbr,
        const unsigned short* __restrict__ Wt,
        const unsigned short* __restrict__ fb,
        const float* __restrict__ bias,
        float* __restrict__ out) {
    // [point][cell] layout (pad 27->28): bank-sequential writes, broadcast reads
    __shared__ int s_idx[4][PPW][28];
    __shared__ int s_vox[4][PPW];

    const int wid  = threadIdx.x >> 6;
    const int lane = threadIdx.x & 63;
    const int wave = blockIdx.x * 4 + wid;
    const int m0   = wave * PPW;

    const int vx0 = (int)ipos[0];
    const int vy0 = (int)ipos[1];
    const int vz0 = (int)ipos[2];

    if (lane < PPW) {
        int m = m0 + lane;
        int vp = -1;
        if (m < M_OUT) {
            vp = ((int)opos[m * 3 + 0] + 1) |
                 (((int)opos[m * 3 + 1] + 1) << 8) |
                 (((int)opos[m * 3 + 2] + 1) << 16);
        }
        s_vox[wid][lane] = vp;
    }
    __syncthreads();

    for (int it = 0; it < 14; ++it) {
        int e = it * 64 + lane;
        if (e < CELLS * PPW) {
            int p = e / CELLS;
            int k = e - p * CELLS;
            int m = m0 + p;
            int id = (m < M_OUT) ? nbr[m * CELLS + k] : 0;
            int ox = k / 9, oy = (k / 3) % 3, oz = k % 3;   // off+1 in 0..2
            int tgt = (vx0 - ox + 2) | ((vy0 - oy + 2) << 8) | ((vz0 - oz + 2) << 16);
            bool valid = (id != 0) | (s_vox[wid][p] == tgt);
            s_idx[wid][p][k] = valid ? id : ZROW;
        }
    }
    __syncthreads();

    const int g = lane >> 4;    // cin group of 8 (MFMA K-slice)
    const int r = lane & 15;    // A row within 16 / B fout within tile

    const unsigned short* fbg = fb + g * 8;
    const unsigned short* wb0 = Wt + r * CIN + g * 8;
    const int* idxr0 = &s_idx[wid][r][0];
    const int* idxr1 = &s_idx[wid][16 + r][0];

    f32x4 acc[8];
#pragma unroll
    for (int i = 0; i < 8; ++i) acc[i] = (f32x4){0.f, 0.f, 0.f, 0.f};

    // --- 2-deep software pipeline: idx (lead 2 cells), A gathers, B tiles ---
    int    pi0[2], pi1[2];
    bf16x8 pa0[2], pa1[2];
    bf16x8 pb[2][4];

    {
        int a0 = idxr0[0], a1 = idxr1[0];
        int b0 = idxr0[1], b1 = idxr1[1];
        pa0[0] = *(const bf16x8*)(fbg + (size_t)a0 * CIN);
        pa1[0] = *(const bf16x8*)(fbg + (size_t)a1 * CIN);
        pa0[1] = *(const bf16x8*)(fbg + (size_t)b0 * CIN);
        pa1[1] = *(const bf16x8*)(fbg + (size_t)b1 * CIN);
#pragma unroll
        for (int t = 0; t < 4; ++t) {
            pb[0][t] = *(const bf16x8*)(wb0 + CELL_OF(0) * (CIN * FOUT) + t * 16 * CIN);
            pb[1][t] = *(const bf16x8*)(wb0 + CELL_OF(1) * (CIN * FOUT) + t * 16 * CIN);
        }
        pi0[0] = idxr0[2]; pi1[0] = idxr1[2];
        pi0[1] = idxr0[3]; pi1[1] = idxr1[3];
    }

#pragma unroll
    for (int k = 0; k < CELLS; ++k) {
        const int s = k & 1;
#pragma unroll
        for (int t = 0; t < 4; ++t) {
            acc[t]     = __builtin_amdgcn_mfma_f32_16x16x32_bf16(pa0[s], pb[s][t], acc[t],     0, 0, 0);
            acc[4 + t] = __builtin_amdgcn_mfma_f32_16x16x32_bf16(pa1[s], pb[s][t], acc[4 + t], 0, 0, 0);
        }
        if (k + 2 < CELLS) {
            pa0[s] = *(const bf16x8*)(fbg + (size_t)pi0[s] * CIN);
            pa1[s] = *(const bf16x8*)(fbg + (size_t)pi1[s] * CIN);
#pragma unroll
            for (int t = 0; t < 4; ++t)
                pb[s][t] = *(const bf16x8*)(wb0 + CELL_OF(k + 2) * (CIN * FOUT) + t * 16 * CIN);
            if (k + 4 < CELLS) {
                pi0[s] = idxr0[k + 4];
                pi1[s] = idxr1[k + 4];
            }
        }
    }

    // D layout: col = lane&15 (fout), row = (lane>>4)*4 + j (point)
    float bb0 = bias[r], bb1 = bias[16 + r], bb2 = bias[32 + r], bb3 = bias[48 + r];
#pragma unroll
    for (int frag = 0; frag < 2; ++frag) {
        int base = m0 + frag * 16 + 4 * g;
#pragma unroll
        for (int j = 0; j < 4; ++j) {
            int m = base + j;
            if (m < M_OUT) {
                float* op = out + (size_t)m * FOUT + r;
                op[0]  = acc[frag * 4 + 0][j] + bb0;
                op[16] = acc[frag * 4 + 1][j] + bb1;
                op[32] = acc[frag * 4 + 2][j] + bb2;
                op[48] = acc[frag * 4 + 3][j] + bb3;
            }
        }
    }
}

extern "C" void kernel_launch(void* const* d_in, const int* in_sizes, int n_in,
                              void* d_out, int out_size, void* d_ws, size_t ws_size,
                              hipStream_t stream) {
    const float* feat = (const float*)d_in[0];
    const float* ipos = (const float*)d_in[1];
    const float* opos = (const float*)d_in[2];
    const float* imp  = (const float*)d_in[4];
    const float* W    = (const float*)d_in[5];
    const float* bias = (const float*)d_in[6];
    const int*   nbr  = (const int*)d_in[7];
    unsigned short* Wt = (unsigned short*)d_ws;
    unsigned short* fb = (unsigned short*)((char*)d_ws + WT_BYTES);
    float* out = (float*)d_out;

    int prep_threads = FB_ROWS * 4 + WT_ELEMS;
    hipLaunchKernelGGL(prep_kernel, dim3((prep_threads + 255) / 256), dim3(256),
                       0, stream, W, feat, imp, Wt, fb);
    hipLaunchKernelGGL(conv32_kernel, dim3(NBLK), dim3(256), 0, stream,
                       opos, ipos, nbr, Wt, fb, bias, out);
}